// Round 3
// baseline (1130.060 us; speedup 1.0000x reference)
//
#include <hip/hip_runtime.h>
#include <hip/hip_bf16.h>
#include <math.h>

#define IGNORE_INDEX (-100)

static constexpr int Bc = 2, Sc = 1024, Dc = 1024, Vc = 128000;
static constexpr int Mrows = Bc * Sc;     // 2048
static constexpr int Kdim = Dc;           // 1024
static constexpr int BM = 128, BN = 128, BK = 64;
static constexpr int NCHUNK = Vc / 64;    // 2000 partial chunks per row

typedef __bf16 bf16x8_t __attribute__((ext_vector_type(8)));
typedef float f32x4_t __attribute__((ext_vector_type(4)));

__device__ __forceinline__ ushort f2bf(float f) {
  union { float f; unsigned u; } v; v.f = f;
  unsigned u = v.u;
  unsigned r = (u + 0x7FFFu + ((u >> 16) & 1u)) >> 16;  // round-nearest-even
  return (ushort)r;
}

// ---------------- cast fp32 -> bf16 (vectorized, grid-stride) ----------------
__global__ void cast_f32_bf16(const float* __restrict__ in, ushort* __restrict__ out,
                              size_t n4) {
  size_t i = (size_t)blockIdx.x * blockDim.x + threadIdx.x;
  size_t stride = (size_t)gridDim.x * blockDim.x;
  for (; i < n4; i += stride) {
    float4 v = reinterpret_cast<const float4*>(in)[i];
    ushort4 o;
    o.x = f2bf(v.x); o.y = f2bf(v.y); o.z = f2bf(v.z); o.w = f2bf(v.w);
    reinterpret_cast<ushort4*>(out)[i] = o;
  }
}

// ---------------- target logits: fp32 dot(hidden[r], weight[t[r]]) ----------------
__global__ void tgt_kernel(const float* __restrict__ hidden, const float* __restrict__ weight,
                           const int* __restrict__ targets, float* __restrict__ tgt) {
  int row = blockIdx.x * 4 + (threadIdx.x >> 6);
  int lane = threadIdx.x & 63;
  if (row >= Mrows) return;
  int t = targets[row];
  float sum = 0.f;
  if (t != IGNORE_INDEX) {
    const float* h = hidden + (size_t)row * Kdim;
    const float* wv = weight + (size_t)t * Kdim;
    for (int k = lane * 4; k < Kdim; k += 64 * 4) {
      float4 a = *reinterpret_cast<const float4*>(h + k);
      float4 b = *reinterpret_cast<const float4*>(wv + k);
      sum += a.x * b.x + a.y * b.y + a.z * b.z + a.w * b.w;
    }
  }
  #pragma unroll
  for (int d = 1; d < 64; d <<= 1) sum += __shfl_xor(sum, d);
  if (lane == 0) tgt[row] = sum;
}

// ---------------- GEMM (bf16 MFMA) + fused partial logsumexp ----------------
// C tile 128x128 per block; 4 waves in 2x2; each wave 64x64 = 4x4 frags of 16x16x32.
// Epilogue: per row, (max, sum-exp) over this wave's 64 cols -> partials[row][chunk].
__global__ __launch_bounds__(256) void gemm_lse(const ushort* __restrict__ Abf,
                                                const ushort* __restrict__ Bbf,
                                                float2* __restrict__ part) {
  __shared__ ushort As[BM * BK];
  __shared__ ushort Bs[BN * BK];
  const int tid = threadIdx.x;
  const int wid = tid >> 6, lane = tid & 63;
  const int wr = wid >> 1, wc = wid & 1;
  const int l15 = lane & 15, l16 = lane >> 4;
  const int mb = blockIdx.x, nb = blockIdx.y;

  f32x4_t acc[4][4];
  #pragma unroll
  for (int i = 0; i < 4; ++i)
    #pragma unroll
    for (int j = 0; j < 4; ++j)
      acc[i][j] = (f32x4_t){0.f, 0.f, 0.f, 0.f};

  const size_t abase = (size_t)mb * BM * Kdim;
  const size_t bbase = (size_t)nb * BN * Kdim;

  for (int k0 = 0; k0 < Kdim; k0 += BK) {
    // stage A and B tiles: 128x64 bf16 each, 16B per lane via global_load_lds
    #pragma unroll
    for (int i = 0; i < 4; ++i) {
      int ci = i * 256 + tid;          // chunk id 0..1023; 8 chunks (128B) per row
      int r = ci >> 3, ko = ci & 7;
      const ushort* ga = Abf + abase + (size_t)r * Kdim + k0 + ko * 8;
      const ushort* gb = Bbf + bbase + (size_t)r * Kdim + k0 + ko * 8;
      __builtin_amdgcn_global_load_lds(
          (const __attribute__((address_space(1))) void*)ga,
          (__attribute__((address_space(3))) void*)(As + ci * 8), 16, 0, 0);
      __builtin_amdgcn_global_load_lds(
          (const __attribute__((address_space(1))) void*)gb,
          (__attribute__((address_space(3))) void*)(Bs + ci * 8), 16, 0, 0);
    }
    __syncthreads();
    #pragma unroll
    for (int kk = 0; kk < 2; ++kk) {
      bf16x8_t afr[4], bfr[4];
      #pragma unroll
      for (int mi = 0; mi < 4; ++mi) {
        int row = wr * 64 + mi * 16 + l15;
        afr[mi] = *reinterpret_cast<const bf16x8_t*>(&As[row * BK + kk * 32 + l16 * 8]);
      }
      #pragma unroll
      for (int ni = 0; ni < 4; ++ni) {
        int col = wc * 64 + ni * 16 + l15;
        bfr[ni] = *reinterpret_cast<const bf16x8_t*>(&Bs[col * BK + kk * 32 + l16 * 8]);
      }
      #pragma unroll
      for (int mi = 0; mi < 4; ++mi)
        #pragma unroll
        for (int ni = 0; ni < 4; ++ni)
          acc[mi][ni] = __builtin_amdgcn_mfma_f32_16x16x32_bf16(afr[mi], bfr[ni],
                                                                acc[mi][ni], 0, 0, 0);
    }
    __syncthreads();
  }

  // fused partial-LSE epilogue.
  // acc[mi][ni][j]: row = wr*64+mi*16+l16*4+j, col = wc*64+ni*16+l15 (m89-verified layout)
  const int chunk = nb * 2 + wc;
  #pragma unroll
  for (int mi = 0; mi < 4; ++mi) {
    #pragma unroll
    for (int j = 0; j < 4; ++j) {
      float v0 = acc[mi][0][j], v1 = acc[mi][1][j], v2 = acc[mi][2][j], v3 = acc[mi][3][j];
      float mloc = fmaxf(fmaxf(v0, v1), fmaxf(v2, v3));
      #pragma unroll
      for (int d = 1; d < 16; d <<= 1) mloc = fmaxf(mloc, __shfl_xor(mloc, d));
      float sloc = __expf(v0 - mloc) + __expf(v1 - mloc) +
                   __expf(v2 - mloc) + __expf(v3 - mloc);
      #pragma unroll
      for (int d = 1; d < 16; d <<= 1) sloc += __shfl_xor(sloc, d);
      if (l15 == 0) {
        int grow = mb * BM + wr * 64 + mi * 16 + l16 * 4 + j;
        part[(size_t)grow * NCHUNK + chunk] = make_float2(mloc, sloc);
      }
    }
  }
}

// ---------------- per-row merge of partials -> nll[row] ----------------
__device__ __forceinline__ void merge_ms(float& m, float& s, float m2, float s2) {
  if (m2 > m) { s = s * __expf(m - m2) + s2; m = m2; }
  else        { s += s2 * __expf(m2 - m); }
}

__global__ void lse_reduce(const float2* __restrict__ part, const float* __restrict__ tgt,
                           const int* __restrict__ targets, float* __restrict__ nll) {
  int row = blockIdx.x;
  const float2* p = part + (size_t)row * NCHUNK;
  float m = -INFINITY, s = 0.f;
  for (int c = threadIdx.x; c < NCHUNK; c += blockDim.x) {
    float2 v = p[c];
    merge_ms(m, s, v.x, v.y);
  }
  #pragma unroll
  for (int d = 1; d < 64; d <<= 1) {
    float m2 = __shfl_xor(m, d), s2 = __shfl_xor(s, d);
    merge_ms(m, s, m2, s2);
  }
  __shared__ float sm[4], ss[4];
  int wid = threadIdx.x >> 6, lane = threadIdx.x & 63;
  if (lane == 0) { sm[wid] = m; ss[wid] = s; }
  __syncthreads();
  if (threadIdx.x == 0) {
    #pragma unroll
    for (int w2 = 1; w2 < 4; ++w2) merge_ms(m, s, sm[w2], ss[w2]);
    int t = targets[row];
    float out = 0.f;
    if (t != IGNORE_INDEX) out = m + logf(s) - tgt[row];
    nll[row] = out;
  }
}

// ---------------- final scalar: sum(nll)/count ----------------
__global__ void final_kernel(const float* __restrict__ nll, const int* __restrict__ targets,
                             float* __restrict__ out) {
  float sum = 0.f, cnt = 0.f;
  for (int i = threadIdx.x; i < Mrows; i += 64) {
    sum += nll[i];
    cnt += (targets[i] != IGNORE_INDEX) ? 1.f : 0.f;
  }
  #pragma unroll
  for (int d = 1; d < 64; d <<= 1) {
    sum += __shfl_xor(sum, d);
    cnt += __shfl_xor(cnt, d);
  }
  if (threadIdx.x == 0)
    out[0] = (cnt == 0.f) ? sum : sum / fmaxf(cnt, 1.f);
}

extern "C" void kernel_launch(void* const* d_in, const int* in_sizes, int n_in,
                              void* d_out, int out_size, void* d_ws, size_t ws_size,
                              hipStream_t stream) {
  const float* hidden = (const float*)d_in[0];   // [2,1024,1024] f32
  const float* weight = (const float*)d_in[1];   // [128000,1024] f32
  const int* targets  = (const int*)d_in[2];     // [2,1024] i32
  float* out = (float*)d_out;

  char* ws = (char*)d_ws;
  size_t off = 0;
  ushort* wbf = (ushort*)(ws + off); off += (size_t)Vc * Dc * sizeof(ushort);      // 262,144,000
  ushort* hbf = (ushort*)(ws + off); off += (size_t)Mrows * Dc * sizeof(ushort);   // 4,194,304
  float2* part = (float2*)(ws + off); off += (size_t)Mrows * NCHUNK * sizeof(float2); // 32,768,000
  float* tgt = (float*)(ws + off); off += Mrows * sizeof(float);
  float* nll = (float*)(ws + off); off += Mrows * sizeof(float);
  (void)ws_size; (void)in_sizes; (void)n_in; (void)out_size;

  cast_f32_bf16<<<2048, 256, 0, stream>>>(weight, wbf, (size_t)Vc * Dc / 4);
  cast_f32_bf16<<<256, 256, 0, stream>>>(hidden, hbf, (size_t)Mrows * Dc / 4);
  tgt_kernel<<<Mrows / 4, 256, 0, stream>>>(hidden, weight, targets, tgt);

  dim3 grid(Mrows / BM, Vc / BN);   // (16, 1000), M fastest-varying for B-tile reuse
  gemm_lse<<<grid, 256, 0, stream>>>(hbf, wbf, part);

  lse_reduce<<<Mrows, 256, 0, stream>>>(part, tgt, targets, nll);
  final_kernel<<<1, 64, 0, stream>>>(nll, targets, out);
}

// Round 4
// 799.895 us; speedup vs baseline: 1.4128x; 1.4128x over previous
//
#include <hip/hip_runtime.h>
#include <hip/hip_bf16.h>
#include <math.h>

#define IGNORE_INDEX (-100)

static constexpr int Dc = 1024, Vc = 128000;
static constexpr int Mrows = 2048;        // B*S
static constexpr int Kdim = Dc;           // 1024
static constexpr int NT = Kdim / 64;      // 16 K-tiles (BK=64, two 32-wide k-halves)
static constexpr int NCHUNK = Vc / 64;    // 2000 partial chunks per row

typedef __bf16 bf16x8_t __attribute__((ext_vector_type(8)));
typedef float f32x4_t __attribute__((ext_vector_type(4)));

__device__ __forceinline__ ushort f2bf(float f) {
  union { float f; unsigned u; } v; v.f = f;
  unsigned u = v.u;
  unsigned r = (u + 0x7FFFu + ((u >> 16) & 1u)) >> 16;  // round-nearest-even
  return (ushort)r;
}

// ---------------- cast fp32 -> bf16 (vectorized, grid-stride) ----------------
__global__ void cast_f32_bf16(const float* __restrict__ in, ushort* __restrict__ out,
                              size_t n4) {
  size_t i = (size_t)blockIdx.x * blockDim.x + threadIdx.x;
  size_t stride = (size_t)gridDim.x * blockDim.x;
  for (; i < n4; i += stride) {
    float4 v = reinterpret_cast<const float4*>(in)[i];
    ushort4 o;
    o.x = f2bf(v.x); o.y = f2bf(v.y); o.z = f2bf(v.z); o.w = f2bf(v.w);
    reinterpret_cast<ushort4*>(out)[i] = o;
  }
}

// ---------------- target logits: fp32 dot(hidden[r], weight[t[r]]) ----------------
__global__ void tgt_kernel(const float* __restrict__ hidden, const float* __restrict__ weight,
                           const int* __restrict__ targets, float* __restrict__ tgt) {
  int row = blockIdx.x * 4 + (threadIdx.x >> 6);
  int lane = threadIdx.x & 63;
  if (row >= Mrows) return;
  int t = targets[row];
  float sum = 0.f;
  if (t != IGNORE_INDEX) {
    const float* h = hidden + (size_t)row * Kdim;
    const float* wv = weight + (size_t)t * Kdim;
    for (int k = lane * 4; k < Kdim; k += 64 * 4) {
      float4 a = *reinterpret_cast<const float4*>(h + k);
      float4 b = *reinterpret_cast<const float4*>(wv + k);
      sum += a.x * b.x + a.y * b.y + a.z * b.z + a.w * b.w;
    }
  }
  #pragma unroll
  for (int d = 1; d < 64; d <<= 1) sum += __shfl_xor(sum, d);
  if (lane == 0) tgt[row] = sum;
}

// ---------------- 256x256 8-wave phased GEMM (bf16 MFMA) + fused partial LSE ----
// LDS: 2 dbuf x 4 regions {A_k0, A_k1, B_k0, B_k1}, each [256 rows][32 k] bf16 =16KB.
// Swizzle: byte ^= ((byte>>6)&3)<<4 (involution; 16B-chunk granular) applied as
// linear LDS dest + inverse-swizzled GLOBAL source + swizzled ds_read (rule #21).
// Waves 2M x 4N, per-wave C = 128x64 (8x4 frags of 16x16x32). 4 phases per K-tile:
// (ks, N-half) quadrants, 16 MFMA each. Counted vmcnt(8) mid-tile + boundary.
__device__ __forceinline__ void stage_region(ushort* region, const ushort* gbase,
                                             int kbase, int tid) {
  #pragma unroll
  for (int ld = 0; ld < 2; ++ld) {
    int c = ld * 512 + tid;            // 16B chunk id, 0..1023 (4 chunks per 64B row)
    int r = c >> 2;
    int ko = (c & 3) ^ (r & 3);        // inverse-swizzled source chunk
    const ushort* g = gbase + (size_t)r * Kdim + kbase + ko * 8;
    __builtin_amdgcn_global_load_lds(
        (const __attribute__((address_space(1))) void*)g,
        (__attribute__((address_space(3))) void*)(region + c * 8), 16, 0, 0);
  }
}

#define MFMA_BF16(A, B, C) __builtin_amdgcn_mfma_f32_16x16x32_bf16((A), (B), (C), 0, 0, 0)

__global__ __launch_bounds__(512, 2) void gemm_lse8(const ushort* __restrict__ Abf,
                                                    const ushort* __restrict__ Bbf,
                                                    float2* __restrict__ part) {
  __shared__ ushort lds[2][4][8192];   // [dbuf][A_k0,A_k1,B_k0,B_k1][256*32] = 128KB
  const int tid = threadIdx.x;
  const int wid = tid >> 6, lane = tid & 63;
  const int wr = wid >> 2, wc = wid & 3;        // 2M x 4N wave grid
  const int l15 = lane & 15, l16 = lane >> 4;
  const int bid = blockIdx.x;
  const int mb = bid & 7;              // bid%8 = XCD -> each XCD owns one A panel
  const int nb = bid >> 3;             // 0..499; all XCDs stream same B panel together

  // swizzled per-lane k-offset within a 64B region row (row&3 == l15&3 for all frags)
  const int koff = (l16 * 16) ^ ((l15 & 3) << 4);
  const int aOff = (wr * 128 + l15) * 64 + koff;   // byte offset of frag base in A region
  const int bOff = (wc * 64 + l15) * 64 + koff;    // byte offset in B region

  const ushort* gA = Abf + (size_t)(mb * 256) * Kdim;
  const ushort* gB = Bbf + (size_t)(nb * 256) * Kdim;

  f32x4_t acc[8][4];
  #pragma unroll
  for (int i = 0; i < 8; ++i)
    #pragma unroll
    for (int j = 0; j < 4; ++j)
      acc[i][j] = (f32x4_t){0.f, 0.f, 0.f, 0.f};

  // prologue: tile0 fully + tile1 k0-halves staged; 12 loads, keep newest 8 in flight
  stage_region(lds[0][0], gA, 0, tid);
  stage_region(lds[0][2], gB, 0, tid);
  stage_region(lds[0][1], gA, 32, tid);
  stage_region(lds[0][3], gB, 32, tid);
  stage_region(lds[1][0], gA, 64, tid);
  stage_region(lds[1][2], gB, 64, tid);
  asm volatile("s_waitcnt vmcnt(8)" ::: "memory");
  __builtin_amdgcn_s_barrier();

  for (int t = 0; t < NT; ++t) {
    const int buf = t & 1, nbuf = buf ^ 1;
    bf16x8_t a[8], b0, b1;

    // ---- phase 1: ks=0, N-frags 0-1 ----
    #pragma unroll
    for (int mi = 0; mi < 8; ++mi)
      a[mi] = *reinterpret_cast<const bf16x8_t*>(
          (const char*)lds[buf][0] + aOff + mi * 1024);
    b0 = *reinterpret_cast<const bf16x8_t*>((const char*)lds[buf][2] + bOff);
    b1 = *reinterpret_cast<const bf16x8_t*>((const char*)lds[buf][2] + bOff + 1024);
    if (t + 1 < NT) stage_region(lds[nbuf][1], gA, (t + 1) * 64 + 32, tid);
    __builtin_amdgcn_s_barrier();
    __builtin_amdgcn_s_setprio(1);
    #pragma unroll
    for (int mi = 0; mi < 8; ++mi) {
      acc[mi][0] = MFMA_BF16(a[mi], b0, acc[mi][0]);
      acc[mi][1] = MFMA_BF16(a[mi], b1, acc[mi][1]);
    }
    __builtin_amdgcn_s_setprio(0);
    __builtin_amdgcn_s_barrier();

    // ---- phase 2: ks=0, N-frags 2-3 (A ks0 frags reused in regs) ----
    b0 = *reinterpret_cast<const bf16x8_t*>((const char*)lds[buf][2] + bOff + 2048);
    b1 = *reinterpret_cast<const bf16x8_t*>((const char*)lds[buf][2] + bOff + 3072);
    if (t + 1 < NT) stage_region(lds[nbuf][3], gB, (t + 1) * 64 + 32, tid);
    __builtin_amdgcn_s_barrier();
    __builtin_amdgcn_s_setprio(1);
    #pragma unroll
    for (int mi = 0; mi < 8; ++mi) {
      acc[mi][2] = MFMA_BF16(a[mi], b0, acc[mi][2]);
      acc[mi][3] = MFMA_BF16(a[mi], b1, acc[mi][3]);
    }
    __builtin_amdgcn_s_setprio(0);
    // mid-tile counted wait: forces A_k1(t)/B_k1(t) landed before all waves read them
    if (t < NT - 1) asm volatile("s_waitcnt vmcnt(8)" ::: "memory");
    else           asm volatile("s_waitcnt vmcnt(0)" ::: "memory");
    __builtin_amdgcn_s_barrier();

    // ---- phase 3: ks=1, N-frags 0-1 ----
    #pragma unroll
    for (int mi = 0; mi < 8; ++mi)
      a[mi] = *reinterpret_cast<const bf16x8_t*>(
          (const char*)lds[buf][1] + aOff + mi * 1024);
    b0 = *reinterpret_cast<const bf16x8_t*>((const char*)lds[buf][3] + bOff);
    b1 = *reinterpret_cast<const bf16x8_t*>((const char*)lds[buf][3] + bOff + 1024);
    if (t + 2 < NT) stage_region(lds[buf][0], gA, (t + 2) * 64, tid);  // ks0 region now free
    __builtin_amdgcn_s_barrier();
    __builtin_amdgcn_s_setprio(1);
    #pragma unroll
    for (int mi = 0; mi < 8; ++mi) {
      acc[mi][0] = MFMA_BF16(a[mi], b0, acc[mi][0]);
      acc[mi][1] = MFMA_BF16(a[mi], b1, acc[mi][1]);
    }
    __builtin_amdgcn_s_setprio(0);
    __builtin_amdgcn_s_barrier();

    // ---- phase 4: ks=1, N-frags 2-3 ----
    b0 = *reinterpret_cast<const bf16x8_t*>((const char*)lds[buf][3] + bOff + 2048);
    b1 = *reinterpret_cast<const bf16x8_t*>((const char*)lds[buf][3] + bOff + 3072);
    if (t + 2 < NT) stage_region(lds[buf][2], gB, (t + 2) * 64, tid);
    __builtin_amdgcn_s_barrier();
    __builtin_amdgcn_s_setprio(1);
    #pragma unroll
    for (int mi = 0; mi < 8; ++mi) {
      acc[mi][2] = MFMA_BF16(a[mi], b0, acc[mi][2]);
      acc[mi][3] = MFMA_BF16(a[mi], b1, acc[mi][3]);
    }
    __builtin_amdgcn_s_setprio(0);
    // boundary counted wait: forces A_k0(t+1)/B_k0(t+1) landed
    asm volatile("s_waitcnt vmcnt(8)" ::: "memory");
    __builtin_amdgcn_s_barrier();
  }

  // fused partial-LSE epilogue. acc[mi][ni][j]: row = wr*128+mi*16+l16*4+j,
  // col = wc*64+ni*16+l15 (m89-verified C/D layout)
  const int chunk = nb * 4 + wc;
  #pragma unroll
  for (int mi = 0; mi < 8; ++mi) {
    #pragma unroll
    for (int j = 0; j < 4; ++j) {
      float v0 = acc[mi][0][j], v1 = acc[mi][1][j], v2 = acc[mi][2][j], v3 = acc[mi][3][j];
      float mloc = fmaxf(fmaxf(v0, v1), fmaxf(v2, v3));
      #pragma unroll
      for (int d = 1; d < 16; d <<= 1) mloc = fmaxf(mloc, __shfl_xor(mloc, d));
      float sloc = __expf(v0 - mloc) + __expf(v1 - mloc) +
                   __expf(v2 - mloc) + __expf(v3 - mloc);
      #pragma unroll
      for (int d = 1; d < 16; d <<= 1) sloc += __shfl_xor(sloc, d);
      if (l15 == 0) {
        int grow = mb * 256 + wr * 128 + mi * 16 + l16 * 4 + j;
        part[(size_t)grow * NCHUNK + chunk] = make_float2(mloc, sloc);
      }
    }
  }
}

// ---------------- per-row merge of partials -> nll[row] ----------------
__device__ __forceinline__ void merge_ms(float& m, float& s, float m2, float s2) {
  if (m2 > m) { s = s * __expf(m - m2) + s2; m = m2; }
  else        { s += s2 * __expf(m2 - m); }
}

__global__ void lse_reduce(const float2* __restrict__ part, const float* __restrict__ tgt,
                           const int* __restrict__ targets, float* __restrict__ nll) {
  int row = blockIdx.x;
  const float2* p = part + (size_t)row * NCHUNK;
  float m = -INFINITY, s = 0.f;
  for (int c = threadIdx.x; c < NCHUNK; c += blockDim.x) {
    float2 v = p[c];
    merge_ms(m, s, v.x, v.y);
  }
  #pragma unroll
  for (int d = 1; d < 64; d <<= 1) {
    float m2 = __shfl_xor(m, d), s2 = __shfl_xor(s, d);
    merge_ms(m, s, m2, s2);
  }
  __shared__ float sm[4], ss[4];
  int wid = threadIdx.x >> 6, lane = threadIdx.x & 63;
  if (lane == 0) { sm[wid] = m; ss[wid] = s; }
  __syncthreads();
  if (threadIdx.x == 0) {
    #pragma unroll
    for (int w2 = 1; w2 < 4; ++w2) merge_ms(m, s, sm[w2], ss[w2]);
    int t = targets[row];
    float out = 0.f;
    if (t != IGNORE_INDEX) out = m + logf(s) - tgt[row];
    nll[row] = out;
  }
}

// ---------------- final scalar: sum(nll)/count ----------------
__global__ void final_kernel(const float* __restrict__ nll, const int* __restrict__ targets,
                             float* __restrict__ out) {
  float sum = 0.f, cnt = 0.f;
  for (int i = threadIdx.x; i < Mrows; i += 64) {
    sum += nll[i];
    cnt += (targets[i] != IGNORE_INDEX) ? 1.f : 0.f;
  }
  #pragma unroll
  for (int d = 1; d < 64; d <<= 1) {
    sum += __shfl_xor(sum, d);
    cnt += __shfl_xor(cnt, d);
  }
  if (threadIdx.x == 0)
    out[0] = (cnt == 0.f) ? sum : sum / fmaxf(cnt, 1.f);
}

extern "C" void kernel_launch(void* const* d_in, const int* in_sizes, int n_in,
                              void* d_out, int out_size, void* d_ws, size_t ws_size,
                              hipStream_t stream) {
  const float* hidden = (const float*)d_in[0];   // [2,1024,1024] f32
  const float* weight = (const float*)d_in[1];   // [128000,1024] f32
  const int* targets  = (const int*)d_in[2];     // [2,1024] i32
  float* out = (float*)d_out;

  char* ws = (char*)d_ws;
  size_t off = 0;
  ushort* wbf = (ushort*)(ws + off); off += (size_t)Vc * Dc * sizeof(ushort);
  ushort* hbf = (ushort*)(ws + off); off += (size_t)Mrows * Dc * sizeof(ushort);
  float2* part = (float2*)(ws + off); off += (size_t)Mrows * NCHUNK * sizeof(float2);
  float* tgt = (float*)(ws + off); off += Mrows * sizeof(float);
  float* nll = (float*)(ws + off); off += Mrows * sizeof(float);
  (void)ws_size; (void)in_sizes; (void)n_in; (void)out_size;

  cast_f32_bf16<<<2048, 256, 0, stream>>>(weight, wbf, (size_t)Vc * Dc / 4);
  cast_f32_bf16<<<256, 256, 0, stream>>>(hidden, hbf, (size_t)Mrows * Dc / 4);
  tgt_kernel<<<Mrows / 4, 256, 0, stream>>>(hidden, weight, targets, tgt);

  gemm_lse8<<<4000, 512, 0, stream>>>(hbf, wbf, part);  // mb=bid&7 (XCD), nb=bid>>3

  lse_reduce<<<Mrows, 256, 0, stream>>>(part, tgt, targets, nll);
  final_kernel<<<1, 64, 0, stream>>>(nll, targets, out);
}

// Round 6
// 797.735 us; speedup vs baseline: 1.4166x; 1.0027x over previous
//
#include <hip/hip_runtime.h>
#include <hip/hip_bf16.h>
#include <math.h>

#define IGNORE_INDEX (-100)

static constexpr int Dc = 1024, Vc = 128000;
static constexpr int Mrows = 2048;        // B*S
static constexpr int Kdim = Dc;           // 1024
static constexpr int NT = Kdim / 64;      // 16 K-tiles (BK=64, two 32-wide k-halves)
static constexpr int NCHUNK = Vc / 64;    // 2000 partial chunks per row

typedef __bf16 bf16x8_t __attribute__((ext_vector_type(8)));
typedef float f32x4_t __attribute__((ext_vector_type(4)));

__device__ __forceinline__ ushort f2bf(float f) {
  union { float f; unsigned u; } v; v.f = f;
  unsigned u = v.u;
  unsigned r = (u + 0x7FFFu + ((u >> 16) & 1u)) >> 16;  // round-nearest-even
  return (ushort)r;
}

// ---------------- cast fp32 -> bf16 (vectorized, grid-stride) ----------------
__global__ void cast_f32_bf16(const float* __restrict__ in, ushort* __restrict__ out,
                              size_t n4) {
  size_t i = (size_t)blockIdx.x * blockDim.x + threadIdx.x;
  size_t stride = (size_t)gridDim.x * blockDim.x;
  for (; i < n4; i += stride) {
    float4 v = reinterpret_cast<const float4*>(in)[i];
    ushort4 o;
    o.x = f2bf(v.x); o.y = f2bf(v.y); o.z = f2bf(v.z); o.w = f2bf(v.w);
    reinterpret_cast<ushort4*>(out)[i] = o;
  }
}

// ---------------- target logits: fp32 dot(hidden[r], weight[t[r]]) ----------------
__global__ void tgt_kernel(const float* __restrict__ hidden, const float* __restrict__ weight,
                           const int* __restrict__ targets, float* __restrict__ tgt) {
  int row = blockIdx.x * 4 + (threadIdx.x >> 6);
  int lane = threadIdx.x & 63;
  if (row >= Mrows) return;
  int t = targets[row];
  float sum = 0.f;
  if (t != IGNORE_INDEX) {
    const float* h = hidden + (size_t)row * Kdim;
    const float* wv = weight + (size_t)t * Kdim;
    for (int k = lane * 4; k < Kdim; k += 64 * 4) {
      float4 a = *reinterpret_cast<const float4*>(h + k);
      float4 b = *reinterpret_cast<const float4*>(wv + k);
      sum += a.x * b.x + a.y * b.y + a.z * b.z + a.w * b.w;
    }
  }
  #pragma unroll
  for (int d = 1; d < 64; d <<= 1) sum += __shfl_xor(sum, d);
  if (lane == 0) tgt[row] = sum;
}

// ---------------- 256x256 8-wave phased GEMM (bf16 MFMA) + fused partial LSE ----
// LDS: 2 dbuf x 4 regions {A_k0, A_k1, B_k0, B_k1}, each [256 rows][32 k] bf16 =16KB.
// Swizzle: 16B-slot s(row) = (row&3) ^ ((row>>2)&3) (involution across the 4 slots
// of a 64B row; balances a wave64 ds_read_b128 to exactly 8 lanes per 4-bank group
// = conflict-free floor). Applied as linear LDS dest + inverse-swizzled GLOBAL
// source + swizzled ds_read offset (rule #21).
__device__ __forceinline__ void stage_region(ushort* region, const ushort* gbase,
                                             int kbase, int tid) {
  #pragma unroll
  for (int ld = 0; ld < 2; ++ld) {
    int c = ld * 512 + tid;            // 16B chunk id, 0..1023 (4 chunks per 64B row)
    int r = c >> 2;
    int ko = (c & 3) ^ (r & 3) ^ ((r >> 2) & 3);   // inverse-swizzled source chunk
    const ushort* g = gbase + (size_t)r * Kdim + kbase + ko * 8;
    __builtin_amdgcn_global_load_lds(
        (const __attribute__((address_space(1))) void*)g,
        (__attribute__((address_space(3))) void*)(region + c * 8), 16, 0, 0);
  }
}

#define MFMA_BF16(A, B, C) __builtin_amdgcn_mfma_f32_16x16x32_bf16((A), (B), (C), 0, 0, 0)

__global__ __launch_bounds__(512, 2) void gemm_lse8(const ushort* __restrict__ Abf,
                                                    const ushort* __restrict__ Bbf,
                                                    float2* __restrict__ part) {
  __shared__ ushort lds[2][4][8192];   // [dbuf][A_k0,A_k1,B_k0,B_k1][256*32] = 128KB
  const int tid = threadIdx.x;
  const int wid = tid >> 6, lane = tid & 63;
  const int wr = wid >> 2, wc = wid & 3;        // 2M x 4N wave grid
  const int l15 = lane & 15, l16 = lane >> 4;
  const int bid = blockIdx.x;
  const int mb = bid & 7;              // bid%8 = XCD -> each XCD owns one A panel
  const int nb = bid >> 3;             // 0..499; all XCDs stream same B panel together

  // swizzled per-lane k-offset within a 64B region row.
  // row = wavebase + l15, wavebase % 16 == 0 -> s(row) = (l15&3)^((l15>>2)&3)
  const int swz = (l15 & 3) ^ ((l15 >> 2) & 3);
  const int koff = (l16 ^ swz) * 16;
  const int aOff = (wr * 128 + l15) * 64 + koff;   // byte offset of frag base in A region
  const int bOff = (wc * 64 + l15) * 64 + koff;    // byte offset in B region

  const ushort* gA = Abf + (size_t)(mb * 256) * Kdim;
  const ushort* gB = Bbf + (size_t)(nb * 256) * Kdim;

  f32x4_t acc[8][4];
  #pragma unroll
  for (int i = 0; i < 8; ++i)
    #pragma unroll
    for (int j = 0; j < 4; ++j)
      acc[i][j] = (f32x4_t){0.f, 0.f, 0.f, 0.f};

  // prologue: tile0 fully + tile1 k0-halves staged; 12 loads, keep newest 8 in flight
  stage_region(lds[0][0], gA, 0, tid);
  stage_region(lds[0][2], gB, 0, tid);
  stage_region(lds[0][1], gA, 32, tid);
  stage_region(lds[0][3], gB, 32, tid);
  stage_region(lds[1][0], gA, 64, tid);
  stage_region(lds[1][2], gB, 64, tid);
  asm volatile("s_waitcnt vmcnt(8)" ::: "memory");
  __builtin_amdgcn_s_barrier();

  for (int t = 0; t < NT; ++t) {
    const int buf = t & 1, nbuf = buf ^ 1;
    bf16x8_t a[8], b0, b1;

    // ---- phase 1: ks=0, N-frags 0-1 ----
    #pragma unroll
    for (int mi = 0; mi < 8; ++mi)
      a[mi] = *reinterpret_cast<const bf16x8_t*>(
          (const char*)lds[buf][0] + aOff + mi * 1024);
    b0 = *reinterpret_cast<const bf16x8_t*>((const char*)lds[buf][2] + bOff);
    b1 = *reinterpret_cast<const bf16x8_t*>((const char*)lds[buf][2] + bOff + 1024);
    if (t + 1 < NT) stage_region(lds[nbuf][1], gA, (t + 1) * 64 + 32, tid);
    __builtin_amdgcn_s_barrier();
    __builtin_amdgcn_s_setprio(1);
    #pragma unroll
    for (int mi = 0; mi < 8; ++mi) {
      acc[mi][0] = MFMA_BF16(a[mi], b0, acc[mi][0]);
      acc[mi][1] = MFMA_BF16(a[mi], b1, acc[mi][1]);
    }
    __builtin_amdgcn_s_setprio(0);
    __builtin_amdgcn_s_barrier();

    // ---- phase 2: ks=0, N-frags 2-3 (A ks0 frags reused in regs) ----
    b0 = *reinterpret_cast<const bf16x8_t*>((const char*)lds[buf][2] + bOff + 2048);
    b1 = *reinterpret_cast<const bf16x8_t*>((const char*)lds[buf][2] + bOff + 3072);
    if (t + 1 < NT) stage_region(lds[nbuf][3], gB, (t + 1) * 64 + 32, tid);
    __builtin_amdgcn_s_barrier();
    __builtin_amdgcn_s_setprio(1);
    #pragma unroll
    for (int mi = 0; mi < 8; ++mi) {
      acc[mi][2] = MFMA_BF16(a[mi], b0, acc[mi][2]);
      acc[mi][3] = MFMA_BF16(a[mi], b1, acc[mi][3]);
    }
    __builtin_amdgcn_s_setprio(0);
    // mid-tile counted wait: forces A_k1(t)/B_k1(t) landed before all waves read them
    if (t < NT - 1) asm volatile("s_waitcnt vmcnt(8)" ::: "memory");
    else           asm volatile("s_waitcnt vmcnt(0)" ::: "memory");
    __builtin_amdgcn_s_barrier();

    // ---- phase 3: ks=1, N-frags 0-1 ----
    #pragma unroll
    for (int mi = 0; mi < 8; ++mi)
      a[mi] = *reinterpret_cast<const bf16x8_t*>(
          (const char*)lds[buf][1] + aOff + mi * 1024);
    b0 = *reinterpret_cast<const bf16x8_t*>((const char*)lds[buf][3] + bOff);
    b1 = *reinterpret_cast<const bf16x8_t*>((const char*)lds[buf][3] + bOff + 1024);
    if (t + 2 < NT) stage_region(lds[buf][0], gA, (t + 2) * 64, tid);  // ks0 region now free
    __builtin_amdgcn_s_barrier();
    __builtin_amdgcn_s_setprio(1);
    #pragma unroll
    for (int mi = 0; mi < 8; ++mi) {
      acc[mi][0] = MFMA_BF16(a[mi], b0, acc[mi][0]);
      acc[mi][1] = MFMA_BF16(a[mi], b1, acc[mi][1]);
    }
    __builtin_amdgcn_s_setprio(0);
    __builtin_amdgcn_s_barrier();

    // ---- phase 4: ks=1, N-frags 2-3 ----
    b0 = *reinterpret_cast<const bf16x8_t*>((const char*)lds[buf][3] + bOff + 2048);
    b1 = *reinterpret_cast<const bf16x8_t*>((const char*)lds[buf][3] + bOff + 3072);
    if (t + 2 < NT) stage_region(lds[buf][2], gB, (t + 2) * 64, tid);
    __builtin_amdgcn_s_barrier();
    __builtin_amdgcn_s_setprio(1);
    #pragma unroll
    for (int mi = 0; mi < 8; ++mi) {
      acc[mi][2] = MFMA_BF16(a[mi], b0, acc[mi][2]);
      acc[mi][3] = MFMA_BF16(a[mi], b1, acc[mi][3]);
    }
    __builtin_amdgcn_s_setprio(0);
    // boundary counted wait: forces A_k0(t+1)/B_k0(t+1) landed
    asm volatile("s_waitcnt vmcnt(8)" ::: "memory");
    __builtin_amdgcn_s_barrier();
  }

  // fused partial-LSE epilogue. acc[mi][ni][j]: row = wr*128+mi*16+l16*4+j,
  // col = wc*64+ni*16+l15 (m89-verified C/D layout)
  const int chunk = nb * 4 + wc;
  #pragma unroll
  for (int mi = 0; mi < 8; ++mi) {
    #pragma unroll
    for (int j = 0; j < 4; ++j) {
      float v0 = acc[mi][0][j], v1 = acc[mi][1][j], v2 = acc[mi][2][j], v3 = acc[mi][3][j];
      float mloc = fmaxf(fmaxf(v0, v1), fmaxf(v2, v3));
      #pragma unroll
      for (int d = 1; d < 16; d <<= 1) mloc = fmaxf(mloc, __shfl_xor(mloc, d));
      float sloc = __expf(v0 - mloc) + __expf(v1 - mloc) +
                   __expf(v2 - mloc) + __expf(v3 - mloc);
      #pragma unroll
      for (int d = 1; d < 16; d <<= 1) sloc += __shfl_xor(sloc, d);
      if (l15 == 0) {
        int grow = mb * 256 + wr * 128 + mi * 16 + l16 * 4 + j;
        part[(size_t)grow * NCHUNK + chunk] = make_float2(mloc, sloc);
      }
    }
  }
}

// ---------------- per-row merge of partials -> nll[row] ----------------
__device__ __forceinline__ void merge_ms(float& m, float& s, float m2, float s2) {
  if (m2 > m) { s = s * __expf(m - m2) + s2; m = m2; }
  else        { s += s2 * __expf(m2 - m); }
}

__global__ void lse_reduce(const float2* __restrict__ part, const float* __restrict__ tgt,
                           const int* __restrict__ targets, float* __restrict__ nll) {
  int row = blockIdx.x;
  const float2* p = part + (size_t)row * NCHUNK;
  float m = -INFINITY, s = 0.f;
  for (int c = threadIdx.x; c < NCHUNK; c += blockDim.x) {
    float2 v = p[c];
    merge_ms(m, s, v.x, v.y);
  }
  #pragma unroll
  for (int d = 1; d < 64; d <<= 1) {
    float m2 = __shfl_xor(m, d), s2 = __shfl_xor(s, d);
    merge_ms(m, s, m2, s2);
  }
  __shared__ float sm[4], ss[4];
  int wid = threadIdx.x >> 6, lane = threadIdx.x & 63;
  if (lane == 0) { sm[wid] = m; ss[wid] = s; }
  __syncthreads();
  if (threadIdx.x == 0) {
    #pragma unroll
    for (int w2 = 1; w2 < 4; ++w2) merge_ms(m, s, sm[w2], ss[w2]);
    int t = targets[row];
    float out = 0.f;
    if (t != IGNORE_INDEX) out = m + logf(s) - tgt[row];
    nll[row] = out;
  }
}

// ---------------- final scalar: sum(nll)/count ----------------
__global__ void final_kernel(const float* __restrict__ nll, const int* __restrict__ targets,
                             float* __restrict__ out) {
  float sum = 0.f, cnt = 0.f;
  for (int i = threadIdx.x; i < Mrows; i += 64) {
    sum += nll[i];
    cnt += (targets[i] != IGNORE_INDEX) ? 1.f : 0.f;
  }
  #pragma unroll
  for (int d = 1; d < 64; d <<= 1) {
    sum += __shfl_xor(sum, d);
    cnt += __shfl_xor(cnt, d);
  }
  if (threadIdx.x == 0)
    out[0] = (cnt == 0.f) ? sum : sum / fmaxf(cnt, 1.f);
}

extern "C" void kernel_launch(void* const* d_in, const int* in_sizes, int n_in,
                              void* d_out, int out_size, void* d_ws, size_t ws_size,
                              hipStream_t stream) {
  const float* hidden = (const float*)d_in[0];   // [2,1024,1024] f32
  const float* weight = (const float*)d_in[1];   // [128000,1024] f32
  const int* targets  = (const int*)d_in[2];     // [2,1024] i32
  float* out = (float*)d_out;

  char* ws = (char*)d_ws;
  size_t off = 0;
  ushort* wbf = (ushort*)(ws + off); off += (size_t)Vc * Dc * sizeof(ushort);
  ushort* hbf = (ushort*)(ws + off); off += (size_t)Mrows * Dc * sizeof(ushort);
  float2* part = (float2*)(ws + off); off += (size_t)Mrows * NCHUNK * sizeof(float2);
  float* tgt = (float*)(ws + off); off += Mrows * sizeof(float);
  float* nll = (float*)(ws + off); off += Mrows * sizeof(float);
  (void)ws_size; (void)in_sizes; (void)n_in; (void)out_size;

  cast_f32_bf16<<<2048, 256, 0, stream>>>(weight, wbf, (size_t)Vc * Dc / 4);
  cast_f32_bf16<<<256, 256, 0, stream>>>(hidden, hbf, (size_t)Mrows * Dc / 4);
  tgt_kernel<<<Mrows / 4, 256, 0, stream>>>(hidden, weight, targets, tgt);

  gemm_lse8<<<4000, 512, 0, stream>>>(hbf, wbf, part);  // mb=bid&7 (XCD), nb=bid>>3

  lse_reduce<<<Mrows, 256, 0, stream>>>(part, tgt, targets, nll);
  final_kernel<<<1, 64, 0, stream>>>(nll, targets, out);
}